// Round 19
// baseline (1040.301 us; speedup 1.0000x reference)
//
#include <hip/hip_runtime.h>
#include <hip/hip_bf16.h>

#define V 50257
#define E 768
#define NH 12
#define NL 4
#define SS 1024
#define BB 2
#define FEE 4
#define HD 64
#define EPSL 1e-5f
#define NPADH 50432   // 197*256

typedef __hip_bfloat16 bf16;
typedef __attribute__((ext_vector_type(8))) short short8;
typedef __attribute__((ext_vector_type(4))) float f32x4;
typedef __attribute__((ext_vector_type(4), aligned(4))) float f32x4a;
typedef __attribute__((ext_vector_type(4))) unsigned short ushort4v;

#define GLD_SRC(p) (const __attribute__((address_space(1))) void*)(p)
#define GLD_DST(p) (__attribute__((address_space(3))) void*)(p)

__device__ __forceinline__ float b2f(bf16 x){ return __bfloat162float(x); }

// ---------------- embed + pos -> bf16 hidden state ----------------
__global__ __launch_bounds__(256) void embed_kernel(const int* __restrict__ x, const float* __restrict__ eW,
                                                    const float* __restrict__ pos, bf16* __restrict__ hb){
  size_t i = (size_t)blockIdx.x*256 + threadIdx.x;
  if (i >= (size_t)BB*SS*E) return;
  int e = (int)(i % E);
  size_t bs = i / E;
  int s = (int)(bs % SS);
  int tok = x[bs];
  hb[i] = __float2bfloat16(eW[(size_t)tok*E + e] + pos[(size_t)s*E + e]);
}

// ---------------- merged: cvt_attn (blocks 0..383) + hmean1 (blocks 384..479) ----------------
__global__ __launch_bounds__(256) void prep_attn(const bf16* __restrict__ hb, bf16* __restrict__ vT,
                                                 float* __restrict__ ph){
  __shared__ short t[64][65];
  int bid = blockIdx.x;
  if (bid < BB*NH*16){
    int st = bid & 15, hh = (bid >> 4) % NH, b = bid / (16*NH);
    int s0 = st*64;
    int c = threadIdx.x & 63, rr = threadIdx.x >> 6;
    #pragma unroll
    for (int i = 0; i < 16; ++i){
      int r = rr*16 + i;
      t[r][c] = __builtin_bit_cast(short, hb[(size_t)(b*SS + s0 + r)*E + hh*HD + c]);
    }
    __syncthreads();
    #pragma unroll
    for (int i = 0; i < 16; ++i){
      int d = rr*16 + i;
      vT[(size_t)((b*NH + hh)*HD + d)*SS + s0 + c] = __builtin_bit_cast(bf16, t[c][d]);
    }
  } else {
    int hbid = bid - BB*NH*16;
    int ec = hbid % 3, tc = (hbid/3) & 15, b = hbid / 48;
    int e = ec*256 + threadIdx.x;
    float s = 0.f;
    #pragma unroll 8
    for (int tt = tc*64; tt < tc*64 + 64; ++tt) s += b2f(hb[((size_t)b*SS + tt)*E + e]);
    ph[((size_t)b*16 + tc)*E + e] = s;
  }
}

// ---------------- flash MFMA attention: KVBLK=128, DOUBLE-BUFFERED K/V, counted waits ----------------
__global__ __launch_bounds__(256) void attn_mfma(const bf16* __restrict__ hb, const bf16* __restrict__ vT,
                                                 bf16* __restrict__ Ab){
  __shared__ short Qs[64*64];          // 8 KB
  __shared__ short Ks[2][128*64];      // 32 KB
  __shared__ short Vs[2][64*128];      // 32 KB
  __shared__ short Ps[4][16*128];      // 8 KB  -> 80 KB total, 2 blocks/CU
  int tid = threadIdx.x, wave = tid >> 6, lane = tid & 63;
  int bid = blockIdx.x;
  int qt = 15 - (bid & 15);            // heavy tiles first
  int hh = (bid >> 4) % NH, b = bid / (16*NH);
  int q0 = qt*64;
  int l15 = lane & 15, l4 = lane >> 4;
  int sw7 = l15 & 7;

  // stage K/V tile kt into buffer bsel (8 loads/thread)
  #define STG_KV(bsel, kt) do {                                                        \
    int k0s = (kt)*128;                                                                \
    _Pragma("unroll")                                                                  \
    for (int rnd = 0; rnd < 4; ++rnd){                                                 \
      int o = rnd*256 + tid; int row = o >> 3; int cs = (((o & 7) ^ (row & 7))*8);     \
      __builtin_amdgcn_global_load_lds(GLD_SRC(hb + ((size_t)(b*SS + k0s + row)*E + hh*HD + cs)), \
                                       GLD_DST(&Ks[bsel][o*8]), 16, 0, 0);             \
    }                                                                                  \
    _Pragma("unroll")                                                                  \
    for (int rnd = 0; rnd < 4; ++rnd){                                                 \
      int o = rnd*256 + tid; int row = o >> 4; int cs = (((o & 15) ^ (row & 15))*8);   \
      __builtin_amdgcn_global_load_lds(GLD_SRC(vT + ((size_t)((b*NH + hh)*HD + row)*SS + k0s + cs)), \
                                       GLD_DST(&Vs[bsel][o*8]), 16, 0, 0);             \
    }                                                                                  \
  } while(0)

  // prologue: Q + first K/V tile, full drain
  #pragma unroll
  for (int rnd = 0; rnd < 2; ++rnd){
    int o = rnd*256 + tid; int row = o >> 3; int cs = (((o & 7) ^ (row & 7))*8);
    __builtin_amdgcn_global_load_lds(GLD_SRC(hb + ((size_t)(b*SS + q0 + row)*E + hh*HD + cs)),
                                     GLD_DST(Qs + o*8), 16, 0, 0);
  }
  STG_KV(0, 0);
  asm volatile("s_waitcnt vmcnt(0)" ::: "memory");
  __builtin_amdgcn_s_barrier();
  __builtin_amdgcn_sched_barrier(0);

  float mrun[4], lrun[4];
  #pragma unroll
  for (int j = 0; j < 4; ++j){ mrun[j] = -1e30f; lrun[j] = 0.f; }
  f32x4 acco[4] = {};

  int nkt = (qt >> 1) + 1;
  for (int kt = 0; kt < nkt; ++kt){
    int k0 = kt*128;
    int cur = kt & 1;
    if (kt + 1 < nkt) STG_KV(cur ^ 1, kt + 1);   // flies under this tile's compute

    f32x4 s[8] = {};
    __builtin_amdgcn_s_setprio(1);
    #pragma unroll
    for (int kk = 0; kk < 2; ++kk){
      int slot = kk*4 + l4;
      short8 af = *(const short8*)&Qs[(wave*16 + l15)*64 + ((slot ^ sw7)*8)];
      #pragma unroll
      for (int n = 0; n < 8; ++n){
        short8 bf8 = *(const short8*)&Ks[cur][(n*16 + l15)*64 + ((slot ^ sw7)*8)];
        s[n] = __builtin_amdgcn_mfma_f32_16x16x32_bf16(af, bf8, s[n], 0, 0, 0);
      }
    }
    __builtin_amdgcn_s_setprio(0);

    bool diag = (kt == nkt - 1);
    #pragma unroll
    for (int j = 0; j < 4; ++j){
      int qg = q0 + wave*16 + l4*4 + j;
      float tmax = -1e30f;
      #pragma unroll
      for (int n = 0; n < 8; ++n){
        float v = s[n][j]*0.125f;
        if (diag && (k0 + n*16 + l15) > qg) v = -1e30f;
        s[n][j] = v; tmax = fmaxf(tmax, v);
      }
      tmax = fmaxf(tmax, __shfl_xor(tmax, 1, 64));
      tmax = fmaxf(tmax, __shfl_xor(tmax, 2, 64));
      tmax = fmaxf(tmax, __shfl_xor(tmax, 4, 64));
      tmax = fmaxf(tmax, __shfl_xor(tmax, 8, 64));
      float mnew = fmaxf(mrun[j], tmax);
      float alpha = __expf(mrun[j] - mnew);
      float rsum = 0.f;
      #pragma unroll
      for (int n = 0; n < 8; ++n){
        float p = __expf(s[n][j] - mnew);
        s[n][j] = p; rsum += p;
      }
      rsum += __shfl_xor(rsum, 1, 64);
      rsum += __shfl_xor(rsum, 2, 64);
      rsum += __shfl_xor(rsum, 4, 64);
      rsum += __shfl_xor(rsum, 8, 64);
      lrun[j] = lrun[j]*alpha + rsum;
      mrun[j] = mnew;
      #pragma unroll
      for (int n = 0; n < 4; ++n) acco[n][j] *= alpha;
      int prow = l4*4 + j;
      #pragma unroll
      for (int n = 0; n < 8; ++n){
        bf16 hv = __float2bfloat16(s[n][j]);
        int slot = (n*2 + (l15 >> 3)) ^ prow;
        Ps[wave][prow*128 + slot*8 + (l15 & 7)] = __builtin_bit_cast(short, hv);
      }
    }
    // Ps is wave-private: same-wave ds_write->ds_read ordered by compiler lgkmcnt

    __builtin_amdgcn_s_setprio(1);
    #pragma unroll
    for (int kk = 0; kk < 4; ++kk){
      int slot = kk*4 + l4;
      short8 pa = *(const short8*)&Ps[wave][l15*128 + ((slot ^ l15)*8)];
      #pragma unroll
      for (int n = 0; n < 4; ++n){
        short8 vb = *(const short8*)&Vs[cur][(n*16 + l15)*128 + ((slot ^ l15)*8)];
        acco[n] = __builtin_amdgcn_mfma_f32_16x16x32_bf16(pa, vb, acco[n], 0, 0, 0);
      }
    }
    __builtin_amdgcn_s_setprio(0);

    if (kt + 1 < nkt){
      asm volatile("s_waitcnt vmcnt(0)" ::: "memory");   // next tile landed
      __builtin_amdgcn_s_barrier();                       // all waves done reading cur
      __builtin_amdgcn_sched_barrier(0);
    }
  }
  #undef STG_KV

  #pragma unroll
  for (int j = 0; j < 4; ++j){
    float inv = 1.f / lrun[j];
    int qg = q0 + wave*16 + l4*4 + j;
    #pragma unroll
    for (int n = 0; n < 4; ++n){
      Ab[(size_t)(b*SS + qg)*E + hh*HD + n*16 + l15] = __float2bfloat16(acco[n][j]*inv);
    }
  }
}

// ---------------- gate stage 1 (hmean stage-2 fused): split-K partial matvec ----------------
__global__ __launch_bounds__(256) void gate1_kernel(const float* __restrict__ ph, const float* __restrict__ gW,
                                                    float* __restrict__ pg){
  int bid = blockIdx.x;                 // (b, kc, ec)
  int ec = bid % 3, kc = (bid/3) & 3, b = bid / 12;
  int nn = ec*256 + threadIdx.x;
  __shared__ float hms[192];
  if (threadIdx.x < 192){
    int k = kc*192 + threadIdx.x;
    float s = 0.f;
    #pragma unroll
    for (int tc = 0; tc < 16; ++tc) s += ph[((size_t)b*16 + tc)*E + k];
    hms[threadIdx.x] = s * (1.0f/SS);
  }
  __syncthreads();
  float acc = 0.f;
  #pragma unroll 8
  for (int j = 0; j < 192; ++j) acc += hms[j] * gW[(size_t)(kc*192 + j)*E + nn];
  pg[((size_t)b*4 + kc)*E + nn] = acc;
}

// ---------------- W[K][N] f32 -> Wt[Npad][K] bf16, batched over layers ----------------
__global__ __launch_bounds__(256) void wcvt_kernel(const float* __restrict__ W, bf16* __restrict__ Wt,
                                                   int K, int N, int Npad){
  int l = blockIdx.z;
  W  += (size_t)l*K*N;
  Wt += (size_t)l*Npad*K;
  __shared__ float t[32][33];
  int n0 = blockIdx.x*32, k0 = blockIdx.y*32;
  int tx = threadIdx.x & 31, ty8 = threadIdx.x >> 5;
  #pragma unroll
  for (int i = 0; i < 4; ++i){
    int k = k0 + ty8 + i*8, n = n0 + tx;
    t[ty8 + i*8][tx] = (k < K && n < N) ? W[(size_t)k*N + n] : 0.f;
  }
  __syncthreads();
  #pragma unroll
  for (int i = 0; i < 4; ++i){
    int n = n0 + ty8 + i*8, k = k0 + tx;
    if (n < Npad && k < K) Wt[(size_t)n*K + k] = __float2bfloat16(t[tx][ty8 + i*8]);
  }
}

// ---------------- 128^2 MFMA GEMM: dbuf, counted-vmcnt pipeline, split-K via z ----------------
// EPI 0: f32 partial (NO bias) to C + z*M*N (vectorized epilogue);
// EPI 3: +bias + gelu, bf16 out, vectorized epilogue (z must be 1)
template<int EPI>
__global__ __launch_bounds__(256, 2) void mfma_gemm(const bf16* __restrict__ A, const bf16* __restrict__ Bt,
                                                    const float* __restrict__ bias, void* __restrict__ Cv,
                                                    int M, int N, int Kslice, int Ktot){
  __shared__ short As[2][128*64];
  __shared__ short Bs[2][128*64];
  int tid = threadIdx.x;
  int wave = tid >> 6, lane = tid & 63;
  int wr = wave >> 1, wc = wave & 1;
  int l15 = lane & 15, l4 = lane >> 4;
  int sw7 = l15 & 7;
  int n0 = blockIdx.x * 128, m0 = blockIdx.y * 128;
  size_t koff = (size_t)blockIdx.z * Kslice;
  f32x4 acc[4][4] = {};
  int srow = tid >> 3;
  int sj = tid & 7;
  const int nks = Kslice >> 6;

  #define STAGE128(bsel, kt) do {                                              \
    int kb = (kt)*64;                                                          \
    _Pragma("unroll")                                                          \
    for (int iss = 0; iss < 4; ++iss){                                         \
      int r = srow + iss*32;                                                   \
      int cs = ((sj ^ (r & 7))*8);                                             \
      __builtin_amdgcn_global_load_lds(GLD_SRC(A + (size_t)(m0 + r)*Ktot + koff + kb + cs),  \
                                       GLD_DST(&As[bsel][r*64 + sj*8]), 16, 0, 0);           \
      __builtin_amdgcn_global_load_lds(GLD_SRC(Bt + (size_t)(n0 + r)*Ktot + koff + kb + cs), \
                                       GLD_DST(&Bs[bsel][r*64 + sj*8]), 16, 0, 0);           \
    }                                                                          \
  } while(0)

  STAGE128(0, 0);
  for (int kt = 0; kt < nks; ++kt){
    int cur = kt & 1;
    if (kt + 1 < nks){
      STAGE128(cur ^ 1, kt + 1);
      asm volatile("s_waitcnt vmcnt(8)" ::: "memory");
    } else {
      asm volatile("s_waitcnt vmcnt(0)" ::: "memory");
    }
    __builtin_amdgcn_s_barrier();
    __builtin_amdgcn_sched_barrier(0);
    __builtin_amdgcn_s_setprio(1);
    #pragma unroll
    for (int kk = 0; kk < 2; ++kk){
      int slot = kk*4 + l4;
      short8 af[4], bfr[4];
      #pragma unroll
      for (int m = 0; m < 4; ++m)
        af[m] = *(const short8*)&As[cur][(wr*64 + m*16 + l15)*64 + ((slot ^ sw7)*8)];
      #pragma unroll
      for (int n = 0; n < 4; ++n)
        bfr[n] = *(const short8*)&Bs[cur][(wc*64 + n*16 + l15)*64 + ((slot ^ sw7)*8)];
      #pragma unroll
      for (int m = 0; m < 4; ++m)
        #pragma unroll
        for (int n = 0; n < 4; ++n)
          acc[m][n] = __builtin_amdgcn_mfma_f32_16x16x32_bf16(af[m], bfr[n], acc[m][n], 0, 0, 0);
    }
    __builtin_amdgcn_s_setprio(0);
    if (kt + 1 < nks){
      __builtin_amdgcn_s_barrier();
      __builtin_amdgcn_sched_barrier(0);
    }
  }
  #undef STAGE128

  // vectorized epilogue: per-wave 16x68 f32 scratch in dead staging LDS
  __syncthreads();
  float* sw = ((float*)&As[0][0]) + wave*1104;
  int rbase = m0 + wr*64;
  int c0w = n0 + wc*64;
  if (EPI == 3){
    bf16* Cb = (bf16*)Cv;
    #pragma unroll
    for (int m = 0; m < 4; ++m){
      #pragma unroll
      for (int n = 0; n < 4; ++n)
        #pragma unroll
        for (int j = 0; j < 4; ++j)
          sw[(l4*4 + j)*68 + n*16 + l15] = acc[m][n][j];
      #pragma unroll
      for (int jj = 0; jj < 4; ++jj){
        int rl = jj*4 + l4;
        f32x4a v = *(const f32x4a*)&sw[rl*68 + l15*4];
        int row = rbase + m*16 + rl;
        int col = c0w + l15*4;
        f32x4a bv = *(const f32x4a*)&bias[col];
        ushort4v o;
        #pragma unroll
        for (int c = 0; c < 4; ++c){
          float t = v[c] + bv[c];
          t = 0.5f*t*(1.0f + erff(t*0.70710678f));
          o[c] = __builtin_bit_cast(unsigned short, __float2bfloat16(t));
        }
        *(ushort4v*)&Cb[(size_t)row*N + col] = o;
      }
    }
  } else {
    float* Cf = (float*)Cv + (size_t)blockIdx.z * M * N;
    #pragma unroll
    for (int m = 0; m < 4; ++m){
      #pragma unroll
      for (int n = 0; n < 4; ++n)
        #pragma unroll
        for (int j = 0; j < 4; ++j)
          sw[(l4*4 + j)*68 + n*16 + l15] = acc[m][n][j];
      #pragma unroll
      for (int jj = 0; jj < 4; ++jj){
        int rl = jj*4 + l4;
        f32x4a v = *(const f32x4a*)&sw[rl*68 + l15*4];
        int row = rbase + m*16 + rl;
        int col = c0w + l15*4;
        if (col + 3 < N){
          *(f32x4a*)&Cf[(size_t)row*N + col] = v;
        } else {
          #pragma unroll
          for (int c = 0; c < 4; ++c) if (col + c < N) Cf[(size_t)row*N + col + c] = v[c];
        }
      }
    }
  }
}

// ---------------- 256^2 head GEMM: 1024 threads = 16 waves of 64x64, BK=64 dbuf, counted vmcnt ----------------
__global__ __launch_bounds__(1024, 4) void gemm256(const bf16* __restrict__ A, const bf16* __restrict__ Bt,
                                                   float* __restrict__ C, int M, int N, int K, int MT){
  __shared__ short As[2][256*64];
  __shared__ short Bs[2][256*64];
  int tid = threadIdx.x;
  int wave = tid >> 6, lane = tid & 63;
  int wr = wave >> 2, wc = wave & 3;        // 4x4 waves, each 64x64
  int l15 = lane & 15, l4 = lane >> 4;
  int sw7 = l15 & 7;

  int lid = blockIdx.x;
  int cpx = gridDim.x >> 3;
  int wg = (lid & 7)*cpx + (lid >> 3);
  int m0 = (wg % MT)*256, n0 = (wg / MT)*256;

  const int nks = K >> 6;

  #define STAGE256(bsel, kt) do {                                             \
    int kb = (kt)*64;                                                         \
    _Pragma("unroll")                                                         \
    for (int i = 0; i < 2; ++i){                                              \
      int o = i*1024 + tid; int r = o >> 3; int sj = o & 7;                   \
      int cs = ((sj ^ (r & 7))*8);                                            \
      __builtin_amdgcn_global_load_lds(GLD_SRC(A + (size_t)(m0 + r)*K + kb + cs),   \
                                       GLD_DST(&As[bsel][r*64 + sj*8]), 16, 0, 0);  \
      __builtin_amdgcn_global_load_lds(GLD_SRC(Bt + (size_t)(n0 + r)*K + kb + cs),  \
                                       GLD_DST(&Bs[bsel][r*64 + sj*8]), 16, 0, 0);  \
    }                                                                         \
  } while(0)

  f32x4 acc[4][4] = {};
  STAGE256(0, 0);
  for (int kt = 0; kt < nks; ++kt){
    int cur = kt & 1;
    if (kt + 1 < nks){
      STAGE256(cur ^ 1, kt + 1);
      asm volatile("s_waitcnt vmcnt(4)" ::: "memory");
    } else {
      asm volatile("s_waitcnt vmcnt(0)" ::: "memory");
    }
    __builtin_amdgcn_s_barrier();
    __builtin_amdgcn_sched_barrier(0);
    __builtin_amdgcn_s_setprio(1);
    #pragma unroll
    for (int kk = 0; kk < 2; ++kk){
      int slot = kk*4 + l4;
      short8 af[4], bfr[4];
      #pragma unroll
      for (int m = 0; m < 4; ++m)
        af[m] = *(const short8*)&As[cur][(wr*64 + m*16 + l15)*64 + ((slot ^ sw7)*8)];
      #pragma unroll
      for (int n = 0; n < 4; ++n)
        bfr[n] = *(const short8*)&Bs[cur][(wc*64 + n*16 + l15)*64 + ((slot ^ sw7)*8)];
      #pragma unroll
      for (int m = 0; m < 4; ++m)
        #pragma unroll
        for (int n = 0; n < 4; ++n)
          acc[m][n] = __builtin_amdgcn_mfma_f32_16x16x32_bf16(af[m], bfr[n], acc[m][n], 0, 0, 0);
    }
    __builtin_amdgcn_s_setprio(0);
    if (kt + 1 < nks){
      __builtin_amdgcn_s_barrier();
      __builtin_amdgcn_sched_barrier(0);
    }
  }
  #undef STAGE256

  // vectorized epilogue: per-wave 16x68 f32 scratch (16 waves x 4416 B = 70 KB of dead 128 KB LDS)
  __syncthreads();
  float* sw = ((float*)&As[0][0]) + wave*1104;
  int rbase = m0 + wr*64;
  int c0w = n0 + wc*64;
  #pragma unroll
  for (int m = 0; m < 4; ++m){
    #pragma unroll
    for (int n = 0; n < 4; ++n)
      #pragma unroll
      for (int j = 0; j < 4; ++j)
        sw[(l4*4 + j)*68 + n*16 + l15] = acc[m][n][j];
    #pragma unroll
    for (int jj = 0; jj < 4; ++jj){
      int rl = jj*4 + l4;
      f32x4a v = *(const f32x4a*)&sw[rl*68 + l15*4];
      int row = rbase + m*16 + rl;
      int col = c0w + l15*4;
      if (col + 3 < N){
        *(f32x4a*)&C[(size_t)row*N + col] = v;
      } else {
        #pragma unroll
        for (int c = 0; c < 4; ++c) if (col + c < N) C[(size_t)row*N + col + c] = v[c];
      }
    }
  }
}

// ---------------- fused: sum split-K parts (+bias) (+gate) (+bf16 resid) + layernorm -> bf16 ----------------
__global__ __launch_bounds__(256) void ln_kernel(const float* __restrict__ parts, int np,
                                                 const float* __restrict__ bias,
                                                 const bf16* __restrict__ residb,
                                                 const float* __restrict__ pg, const float* __restrict__ gb,
                                                 const float* __restrict__ g, const float* __restrict__ bta,
                                                 bf16* __restrict__ outb){
  const size_t PS = (size_t)BB*SS*E;   // partial stride
  int row = blockIdx.x;
  int b = row >> 10;
  int tid = threadIdx.x;
  __shared__ float sred[4];
  float y[3];
  float lsum = 0.f;
  #pragma unroll
  for (int i = 0; i < 3; ++i){
    int e = tid + i*256;
    float v = bias ? bias[e] : 0.f;
    for (int p = 0; p < np; ++p) v += parts[(size_t)p*PS + (size_t)row*E + e];
    if (pg){
      float ga = pg[(size_t)(b*4+0)*E + e] + pg[(size_t)(b*4+1)*E + e]
               + pg[(size_t)(b*4+2)*E + e] + pg[(size_t)(b*4+3)*E + e] + gb[e];
      v *= 1.0f / (1.0f + __expf(-ga));
    }
    if (residb) v += b2f(residb[(size_t)row*E + e]);
    y[i] = v; lsum += v;
  }
  for (int off = 32; off > 0; off >>= 1) lsum += __shfl_down(lsum, off, 64);
  int wid = tid >> 6, lane = tid & 63;
  if (lane == 0) sred[wid] = lsum;
  __syncthreads();
  float mean = (sred[0]+sred[1]+sred[2]+sred[3]) * (1.0f/E);
  __syncthreads();
  float lvar = 0.f;
  #pragma unroll
  for (int i = 0; i < 3; ++i){ float d = y[i]-mean; lvar += d*d; }
  for (int off = 32; off > 0; off >>= 1) lvar += __shfl_down(lvar, off, 64);
  if (lane == 0) sred[wid] = lvar;
  __syncthreads();
  float rstd = rsqrtf((sred[0]+sred[1]+sred[2]+sred[3]) * (1.0f/E) + EPSL);
  __syncthreads();
  #pragma unroll
  for (int i = 0; i < 3; ++i){
    int e = tid + i*256;
    outb[(size_t)row*E + e] = __float2bfloat16((y[i]-mean)*rstd*g[e] + bta[e]);
  }
}

extern "C" void kernel_launch(void* const* d_in, const int* in_sizes, int n_in,
                              void* d_out, int out_size, void* d_ws, size_t ws_size,
                              hipStream_t stream) {
  const int*   x      = (const int*)  d_in[0];
  const float* embedW = (const float*)d_in[2];
  const float* pos    = (const float*)d_in[3];
  const float* fcW    = (const float*)d_in[4];
  const float* fcB    = (const float*)d_in[5];
  const float* gW     = (const float*)d_in[6];
  const float* gB     = (const float*)d_in[7];
  const float* ln1g   = (const float*)d_in[8];
  const float* ln1b   = (const float*)d_in[9];
  const float* ln2g   = (const float*)d_in[10];
  const float* ln2b   = (const float*)d_in[11];
  const float* f1W    = (const float*)d_in[12];
  const float* f1B    = (const float*)d_in[13];
  const float* f2W    = (const float*)d_in[14];
  const float* f2B    = (const float*)d_in[15];
  const float* lnfg   = (const float*)d_in[16];
  const float* lnfb   = (const float*)d_in[17];
  const float* headW  = (const float*)d_in[18];
  float* out = (float*)d_out;

  const size_t BSE = (size_t)BB*SS*E;
  float* o    = (float*)d_ws;              // hb + vT (bf16) live here
  float* tmp  = o   + BSE;                 // 2*BSE: split-K partials
  float* ph   = tmp + 2*BSE;               // [BB*16][E]
  float* pg   = ph  + (size_t)BB*16*E;     // [BB*4][E]
  bf16* abA   = (bf16*)(pg + (size_t)BB*4*E);   // [2048][768]
  bf16* abF   = abA + BSE;                      // [2048][3072]
  bf16* WfcT  = abF + BSE*FEE;                  // [NL][768][768]
  bf16* Wf1T  = WfcT + (size_t)NL*E*E;          // [NL][3072][768]
  bf16* Wf2T  = Wf1T + (size_t)NL*FEE*E*E;      // [NL][768][3072]
  bf16* WheadT= Wf2T + (size_t)NL*FEE*E*E;      // [NPADH][768]
  bf16* hb    = (bf16*)o;
  bf16* vT    = hb + BSE;

  const int rows = BB*SS;   // 2048

  embed_kernel<<<(int)((BSE + 255)/256), 256, 0, stream>>>(x, embedW, pos, hb);

  { dim3 g(E/32, E/32, NL);        wcvt_kernel<<<g, 256, 0, stream>>>(fcW, WfcT, E, E, E); }
  { dim3 g((FEE*E)/32, E/32, NL);  wcvt_kernel<<<g, 256, 0, stream>>>(f1W, Wf1T, E, FEE*E, FEE*E); }
  { dim3 g(E/32, (FEE*E)/32, NL);  wcvt_kernel<<<g, 256, 0, stream>>>(f2W, Wf2T, FEE*E, E, E); }
  { dim3 g(NPADH/32, E/32, 1);     wcvt_kernel<<<g, 256, 0, stream>>>(headW, WheadT, E, V, NPADH); }

  for (int l = 0; l < NL; ++l){
    size_t oEE = (size_t)l*E*E, oE = (size_t)l*E, oFb = (size_t)l*FEE*E;

    prep_attn<<<BB*NH*16 + BB*16*3, 256, 0, stream>>>(hb, vT, ph);
    attn_mfma<<<BB*NH*16, 256, 0, stream>>>(hb, vT, abA);
    gate1_kernel<<<BB*4*3, 256, 0, stream>>>(ph, gW + oEE, pg);

    // fc_out: (2048x768) @ (768x768), split-K2 -> tmp partials
    { dim3 g(E/128, rows/128, 2);
      mfma_gemm<0><<<g, 256, 0, stream>>>(abA, WfcT + oEE, nullptr, tmp, rows, E, E/2, E); }

    // ln1: sum 2 parts + fcB, gate from pg/gB, + resid hb -> abA (bf16, ff1 input + ln2 resid)
    ln_kernel<<<rows, 256, 0, stream>>>(tmp, 2, fcB + oE, hb, pg, gB + oE,
                                        ln1g + oE, ln1b + oE, abA);

    // ff1: (2048x768) @ (768x3072) + gelu -> abF bf16
    { dim3 g((FEE*E)/128, rows/128, 1);
      mfma_gemm<3><<<g, 256, 0, stream>>>(abA, Wf1T + (size_t)l*FEE*E*E, f1B + oFb, abF, rows, FEE*E, E, E); }

    // ff2: (2048x3072) @ (3072x768), split-K2 -> tmp partials
    { dim3 g(E/128, rows/128, 2);
      mfma_gemm<0><<<g, 256, 0, stream>>>(abF, Wf2T + (size_t)l*FEE*E*E, nullptr, tmp, rows, E, FEE*E/2, FEE*E); }

    // ln2: sum 2 parts + f2B, + resid abA -> hb (bf16, next layer's hidden state)
    ln_kernel<<<rows, 256, 0, stream>>>(tmp, 2, f2B + oE, abA, nullptr, nullptr,
                                        ln2g + oE, ln2b + oE, hb);
  }

  // final LN: input = hb alone -> abA (head input)
  ln_kernel<<<rows, 256, 0, stream>>>(nullptr, 0, nullptr, hb, nullptr, nullptr,
                                      lnfg, lnfb, abA);
  {
    gemm256<<<(rows/256)*(NPADH/256), 1024, 0, stream>>>(abA, WheadT, out, rows, V, E, rows/256);
  }
}

// Round 20
// 965.491 us; speedup vs baseline: 1.0775x; 1.0775x over previous
//
#include <hip/hip_runtime.h>
#include <hip/hip_bf16.h>

#define V 50257
#define E 768
#define NH 12
#define NL 4
#define SS 1024
#define BB 2
#define FEE 4
#define HD 64
#define EPSL 1e-5f
#define NPADH 50432   // 197*256

typedef __hip_bfloat16 bf16;
typedef __attribute__((ext_vector_type(8))) short short8;
typedef __attribute__((ext_vector_type(4))) float f32x4;
typedef __attribute__((ext_vector_type(4), aligned(4))) float f32x4a;
typedef __attribute__((ext_vector_type(4))) unsigned short ushort4v;

#define GLD_SRC(p) (const __attribute__((address_space(1))) void*)(p)
#define GLD_DST(p) (__attribute__((address_space(3))) void*)(p)

__device__ __forceinline__ float b2f(bf16 x){ return __bfloat162float(x); }

// ---------------- embed + pos -> bf16 hidden state ----------------
__global__ __launch_bounds__(256) void embed_kernel(const int* __restrict__ x, const float* __restrict__ eW,
                                                    const float* __restrict__ pos, bf16* __restrict__ hb){
  size_t i = (size_t)blockIdx.x*256 + threadIdx.x;
  if (i >= (size_t)BB*SS*E) return;
  int e = (int)(i % E);
  size_t bs = i / E;
  int s = (int)(bs % SS);
  int tok = x[bs];
  hb[i] = __float2bfloat16(eW[(size_t)tok*E + e] + pos[(size_t)s*E + e]);
}

// ---------------- merged: cvt_attn (blocks 0..383) + hmean1 (blocks 384..479) ----------------
__global__ __launch_bounds__(256) void prep_attn(const bf16* __restrict__ hb, bf16* __restrict__ vT,
                                                 float* __restrict__ ph){
  __shared__ short t[64][65];
  int bid = blockIdx.x;
  if (bid < BB*NH*16){
    int st = bid & 15, hh = (bid >> 4) % NH, b = bid / (16*NH);
    int s0 = st*64;
    int c = threadIdx.x & 63, rr = threadIdx.x >> 6;
    #pragma unroll
    for (int i = 0; i < 16; ++i){
      int r = rr*16 + i;
      t[r][c] = __builtin_bit_cast(short, hb[(size_t)(b*SS + s0 + r)*E + hh*HD + c]);
    }
    __syncthreads();
    #pragma unroll
    for (int i = 0; i < 16; ++i){
      int d = rr*16 + i;
      vT[(size_t)((b*NH + hh)*HD + d)*SS + s0 + c] = __builtin_bit_cast(bf16, t[c][d]);
    }
  } else {
    int hbid = bid - BB*NH*16;
    int ec = hbid % 3, tc = (hbid/3) & 15, b = hbid / 48;
    int e = ec*256 + threadIdx.x;
    float s = 0.f;
    #pragma unroll 8
    for (int tt = tc*64; tt < tc*64 + 64; ++tt) s += b2f(hb[((size_t)b*SS + tt)*E + e]);
    ph[((size_t)b*16 + tc)*E + e] = s;
  }
}

// ---------------- flash MFMA attention (KVBLK=128, slot-swizzled LDS) ----------------
__global__ __launch_bounds__(256) void attn_mfma(const bf16* __restrict__ hb, const bf16* __restrict__ vT,
                                                 bf16* __restrict__ Ab){
  __shared__ short Qs[64*64];
  __shared__ short Ks[128*64];
  __shared__ short Vs[64*128];
  __shared__ short Ps[4][16*128];
  int tid = threadIdx.x, wave = tid >> 6, lane = tid & 63;
  int bid = blockIdx.x;
  int qt = 15 - (bid & 15);              // heavy tiles first
  int hh = (bid >> 4) % NH, b = bid / (16*NH);
  int q0 = qt*64;
  int l15 = lane & 15, l4 = lane >> 4;
  int sw7 = l15 & 7;

  #pragma unroll
  for (int rnd = 0; rnd < 2; ++rnd){
    int o = rnd*256 + tid; int row = o >> 3; int cs = (((o & 7) ^ (row & 7))*8);
    __builtin_amdgcn_global_load_lds(GLD_SRC(hb + ((size_t)(b*SS + q0 + row)*E + hh*HD + cs)),
                                     GLD_DST(Qs + o*8), 16, 0, 0);
  }

  float mrun[4], lrun[4];
  #pragma unroll
  for (int j = 0; j < 4; ++j){ mrun[j] = -1e30f; lrun[j] = 0.f; }
  f32x4 acco[4] = {};

  int nkt = (qt >> 1) + 1;
  for (int kt = 0; kt < nkt; ++kt){
    int k0 = kt*128;
    __syncthreads();
    #pragma unroll
    for (int rnd = 0; rnd < 4; ++rnd){
      int o = rnd*256 + tid; int row = o >> 3; int cs = (((o & 7) ^ (row & 7))*8);
      __builtin_amdgcn_global_load_lds(GLD_SRC(hb + ((size_t)(b*SS + k0 + row)*E + hh*HD + cs)),
                                       GLD_DST(Ks + o*8), 16, 0, 0);
    }
    #pragma unroll
    for (int rnd = 0; rnd < 4; ++rnd){
      int o = rnd*256 + tid; int row = o >> 4; int cs = (((o & 15) ^ (row & 15))*8);
      __builtin_amdgcn_global_load_lds(GLD_SRC(vT + ((size_t)((b*NH + hh)*HD + row)*SS + k0 + cs)),
                                       GLD_DST(Vs + o*8), 16, 0, 0);
    }
    __syncthreads();

    f32x4 s[8] = {};
    __builtin_amdgcn_s_setprio(1);
    #pragma unroll
    for (int kk = 0; kk < 2; ++kk){
      int slot = kk*4 + l4;
      short8 af = *(const short8*)&Qs[(wave*16 + l15)*64 + ((slot ^ sw7)*8)];
      #pragma unroll
      for (int n = 0; n < 8; ++n){
        short8 bf8 = *(const short8*)&Ks[(n*16 + l15)*64 + ((slot ^ sw7)*8)];
        s[n] = __builtin_amdgcn_mfma_f32_16x16x32_bf16(af, bf8, s[n], 0, 0, 0);
      }
    }
    __builtin_amdgcn_s_setprio(0);

    bool diag = (kt == nkt - 1);
    #pragma unroll
    for (int j = 0; j < 4; ++j){
      int qg = q0 + wave*16 + l4*4 + j;
      float tmax = -1e30f;
      #pragma unroll
      for (int n = 0; n < 8; ++n){
        float v = s[n][j]*0.125f;
        if (diag && (k0 + n*16 + l15) > qg) v = -1e30f;
        s[n][j] = v; tmax = fmaxf(tmax, v);
      }
      tmax = fmaxf(tmax, __shfl_xor(tmax, 1, 64));
      tmax = fmaxf(tmax, __shfl_xor(tmax, 2, 64));
      tmax = fmaxf(tmax, __shfl_xor(tmax, 4, 64));
      tmax = fmaxf(tmax, __shfl_xor(tmax, 8, 64));
      float mnew = fmaxf(mrun[j], tmax);
      float alpha = __expf(mrun[j] - mnew);
      float rsum = 0.f;
      #pragma unroll
      for (int n = 0; n < 8; ++n){
        float p = __expf(s[n][j] - mnew);
        s[n][j] = p; rsum += p;
      }
      rsum += __shfl_xor(rsum, 1, 64);
      rsum += __shfl_xor(rsum, 2, 64);
      rsum += __shfl_xor(rsum, 4, 64);
      rsum += __shfl_xor(rsum, 8, 64);
      lrun[j] = lrun[j]*alpha + rsum;
      mrun[j] = mnew;
      #pragma unroll
      for (int n = 0; n < 4; ++n) acco[n][j] *= alpha;
      int prow = l4*4 + j;
      #pragma unroll
      for (int n = 0; n < 8; ++n){
        bf16 hv = __float2bfloat16(s[n][j]);
        int slot = (n*2 + (l15 >> 3)) ^ prow;
        Ps[wave][prow*128 + slot*8 + (l15 & 7)] = __builtin_bit_cast(short, hv);
      }
    }
    __syncthreads();

    __builtin_amdgcn_s_setprio(1);
    #pragma unroll
    for (int kk = 0; kk < 4; ++kk){
      int slot = kk*4 + l4;
      short8 pa = *(const short8*)&Ps[wave][l15*128 + ((slot ^ l15)*8)];
      #pragma unroll
      for (int n = 0; n < 4; ++n){
        short8 vb = *(const short8*)&Vs[(n*16 + l15)*128 + ((slot ^ l15)*8)];
        acco[n] = __builtin_amdgcn_mfma_f32_16x16x32_bf16(pa, vb, acco[n], 0, 0, 0);
      }
    }
    __builtin_amdgcn_s_setprio(0);
  }

  #pragma unroll
  for (int j = 0; j < 4; ++j){
    float inv = 1.f / lrun[j];
    int qg = q0 + wave*16 + l4*4 + j;
    #pragma unroll
    for (int n = 0; n < 4; ++n){
      Ab[(size_t)(b*SS + qg)*E + hh*HD + n*16 + l15] = __float2bfloat16(acco[n][j]*inv);
    }
  }
}

// ---------------- gate stage 1 (hmean stage-2 fused): split-K partial matvec ----------------
__global__ __launch_bounds__(256) void gate1_kernel(const float* __restrict__ ph, const float* __restrict__ gW,
                                                    float* __restrict__ pg){
  int bid = blockIdx.x;                 // (b, kc, ec)
  int ec = bid % 3, kc = (bid/3) & 3, b = bid / 12;
  int nn = ec*256 + threadIdx.x;
  __shared__ float hms[192];
  if (threadIdx.x < 192){
    int k = kc*192 + threadIdx.x;
    float s = 0.f;
    #pragma unroll
    for (int tc = 0; tc < 16; ++tc) s += ph[((size_t)b*16 + tc)*E + k];
    hms[threadIdx.x] = s * (1.0f/SS);
  }
  __syncthreads();
  float acc = 0.f;
  #pragma unroll 8
  for (int j = 0; j < 192; ++j) acc += hms[j] * gW[(size_t)(kc*192 + j)*E + nn];
  pg[((size_t)b*4 + kc)*E + nn] = acc;
}

// ---------------- W[K][N] f32 -> Wt[Npad][K] bf16, batched over layers ----------------
__global__ __launch_bounds__(256) void wcvt_kernel(const float* __restrict__ W, bf16* __restrict__ Wt,
                                                   int K, int N, int Npad){
  int l = blockIdx.z;
  W  += (size_t)l*K*N;
  Wt += (size_t)l*Npad*K;
  __shared__ float t[32][33];
  int n0 = blockIdx.x*32, k0 = blockIdx.y*32;
  int tx = threadIdx.x & 31, ty8 = threadIdx.x >> 5;
  #pragma unroll
  for (int i = 0; i < 4; ++i){
    int k = k0 + ty8 + i*8, n = n0 + tx;
    t[ty8 + i*8][tx] = (k < K && n < N) ? W[(size_t)k*N + n] : 0.f;
  }
  __syncthreads();
  #pragma unroll
  for (int i = 0; i < 4; ++i){
    int n = n0 + ty8 + i*8, k = k0 + tx;
    if (n < Npad && k < K) Wt[(size_t)n*K + k] = __float2bfloat16(t[tx][ty8 + i*8]);
  }
}

// ---------------- 128^2 MFMA GEMM: dbuf, counted-vmcnt pipeline, split-K via z ----------------
// EPI 0: f32 partial (NO bias) to C + z*M*N (vectorized epilogue);
// EPI 3: +bias + gelu, bf16 out, vectorized epilogue (z must be 1)
template<int EPI>
__global__ __launch_bounds__(256, 2) void mfma_gemm(const bf16* __restrict__ A, const bf16* __restrict__ Bt,
                                                    const float* __restrict__ bias, void* __restrict__ Cv,
                                                    int M, int N, int Kslice, int Ktot){
  __shared__ short As[2][128*64];
  __shared__ short Bs[2][128*64];
  int tid = threadIdx.x;
  int wave = tid >> 6, lane = tid & 63;
  int wr = wave >> 1, wc = wave & 1;
  int l15 = lane & 15, l4 = lane >> 4;
  int sw7 = l15 & 7;
  int n0 = blockIdx.x * 128, m0 = blockIdx.y * 128;
  size_t koff = (size_t)blockIdx.z * Kslice;
  f32x4 acc[4][4] = {};
  int srow = tid >> 3;
  int sj = tid & 7;
  const int nks = Kslice >> 6;

  #define STAGE128(bsel, kt) do {                                              \
    int kb = (kt)*64;                                                          \
    _Pragma("unroll")                                                          \
    for (int iss = 0; iss < 4; ++iss){                                         \
      int r = srow + iss*32;                                                   \
      int cs = ((sj ^ (r & 7))*8);                                             \
      __builtin_amdgcn_global_load_lds(GLD_SRC(A + (size_t)(m0 + r)*Ktot + koff + kb + cs),  \
                                       GLD_DST(&As[bsel][r*64 + sj*8]), 16, 0, 0);           \
      __builtin_amdgcn_global_load_lds(GLD_SRC(Bt + (size_t)(n0 + r)*Ktot + koff + kb + cs), \
                                       GLD_DST(&Bs[bsel][r*64 + sj*8]), 16, 0, 0);           \
    }                                                                          \
  } while(0)

  STAGE128(0, 0);
  for (int kt = 0; kt < nks; ++kt){
    int cur = kt & 1;
    if (kt + 1 < nks){
      STAGE128(cur ^ 1, kt + 1);
      asm volatile("s_waitcnt vmcnt(8)" ::: "memory");
    } else {
      asm volatile("s_waitcnt vmcnt(0)" ::: "memory");
    }
    __builtin_amdgcn_s_barrier();
    __builtin_amdgcn_sched_barrier(0);
    __builtin_amdgcn_s_setprio(1);
    #pragma unroll
    for (int kk = 0; kk < 2; ++kk){
      int slot = kk*4 + l4;
      short8 af[4], bfr[4];
      #pragma unroll
      for (int m = 0; m < 4; ++m)
        af[m] = *(const short8*)&As[cur][(wr*64 + m*16 + l15)*64 + ((slot ^ sw7)*8)];
      #pragma unroll
      for (int n = 0; n < 4; ++n)
        bfr[n] = *(const short8*)&Bs[cur][(wc*64 + n*16 + l15)*64 + ((slot ^ sw7)*8)];
      #pragma unroll
      for (int m = 0; m < 4; ++m)
        #pragma unroll
        for (int n = 0; n < 4; ++n)
          acc[m][n] = __builtin_amdgcn_mfma_f32_16x16x32_bf16(af[m], bfr[n], acc[m][n], 0, 0, 0);
    }
    __builtin_amdgcn_s_setprio(0);
    if (kt + 1 < nks){
      __builtin_amdgcn_s_barrier();
      __builtin_amdgcn_sched_barrier(0);
    }
  }
  #undef STAGE128

  // vectorized epilogue: per-wave 16x68 f32 scratch in dead staging LDS
  __syncthreads();
  float* sw = ((float*)&As[0][0]) + wave*1104;
  int rbase = m0 + wr*64;
  int c0w = n0 + wc*64;
  if (EPI == 3){
    bf16* Cb = (bf16*)Cv;
    #pragma unroll
    for (int m = 0; m < 4; ++m){
      #pragma unroll
      for (int n = 0; n < 4; ++n)
        #pragma unroll
        for (int j = 0; j < 4; ++j)
          sw[(l4*4 + j)*68 + n*16 + l15] = acc[m][n][j];
      #pragma unroll
      for (int jj = 0; jj < 4; ++jj){
        int rl = jj*4 + l4;
        f32x4a v = *(const f32x4a*)&sw[rl*68 + l15*4];
        int row = rbase + m*16 + rl;
        int col = c0w + l15*4;
        f32x4a bv = *(const f32x4a*)&bias[col];
        ushort4v o;
        #pragma unroll
        for (int c = 0; c < 4; ++c){
          float t = v[c] + bv[c];
          t = 0.5f*t*(1.0f + erff(t*0.70710678f));
          o[c] = __builtin_bit_cast(unsigned short, __float2bfloat16(t));
        }
        *(ushort4v*)&Cb[(size_t)row*N + col] = o;
      }
    }
  } else {
    float* Cf = (float*)Cv + (size_t)blockIdx.z * M * N;
    #pragma unroll
    for (int m = 0; m < 4; ++m){
      #pragma unroll
      for (int n = 0; n < 4; ++n)
        #pragma unroll
        for (int j = 0; j < 4; ++j)
          sw[(l4*4 + j)*68 + n*16 + l15] = acc[m][n][j];
      #pragma unroll
      for (int jj = 0; jj < 4; ++jj){
        int rl = jj*4 + l4;
        f32x4a v = *(const f32x4a*)&sw[rl*68 + l15*4];
        int row = rbase + m*16 + rl;
        int col = c0w + l15*4;
        if (col + 3 < N){
          *(f32x4a*)&Cf[(size_t)row*N + col] = v;
        } else {
          #pragma unroll
          for (int c = 0; c < 4; ++c) if (col + c < N) Cf[(size_t)row*N + col + c] = v[c];
        }
      }
    }
  }
}

// ---------------- 256^2 head GEMM: 1024 threads = 16 waves of 64x64, BK=64 dbuf, counted vmcnt ----------------
__global__ __launch_bounds__(1024, 4) void gemm256(const bf16* __restrict__ A, const bf16* __restrict__ Bt,
                                                   float* __restrict__ C, int M, int N, int K, int MT){
  __shared__ short As[2][256*64];
  __shared__ short Bs[2][256*64];
  int tid = threadIdx.x;
  int wave = tid >> 6, lane = tid & 63;
  int wr = wave >> 2, wc = wave & 3;        // 4x4 waves, each 64x64
  int l15 = lane & 15, l4 = lane >> 4;
  int sw7 = l15 & 7;

  int lid = blockIdx.x;
  int cpx = gridDim.x >> 3;
  int wg = (lid & 7)*cpx + (lid >> 3);
  int m0 = (wg % MT)*256, n0 = (wg / MT)*256;

  const int nks = K >> 6;

  #define STAGE256(bsel, kt) do {                                             \
    int kb = (kt)*64;                                                         \
    _Pragma("unroll")                                                         \
    for (int i = 0; i < 2; ++i){                                              \
      int o = i*1024 + tid; int r = o >> 3; int sj = o & 7;                   \
      int cs = ((sj ^ (r & 7))*8);                                            \
      __builtin_amdgcn_global_load_lds(GLD_SRC(A + (size_t)(m0 + r)*K + kb + cs),   \
                                       GLD_DST(&As[bsel][r*64 + sj*8]), 16, 0, 0);  \
      __builtin_amdgcn_global_load_lds(GLD_SRC(Bt + (size_t)(n0 + r)*K + kb + cs),  \
                                       GLD_DST(&Bs[bsel][r*64 + sj*8]), 16, 0, 0);  \
    }                                                                         \
  } while(0)

  f32x4 acc[4][4] = {};
  STAGE256(0, 0);
  for (int kt = 0; kt < nks; ++kt){
    int cur = kt & 1;
    if (kt + 1 < nks){
      STAGE256(cur ^ 1, kt + 1);
      asm volatile("s_waitcnt vmcnt(4)" ::: "memory");
    } else {
      asm volatile("s_waitcnt vmcnt(0)" ::: "memory");
    }
    __builtin_amdgcn_s_barrier();
    __builtin_amdgcn_sched_barrier(0);
    __builtin_amdgcn_s_setprio(1);
    #pragma unroll
    for (int kk = 0; kk < 2; ++kk){
      int slot = kk*4 + l4;
      short8 af[4], bfr[4];
      #pragma unroll
      for (int m = 0; m < 4; ++m)
        af[m] = *(const short8*)&As[cur][(wr*64 + m*16 + l15)*64 + ((slot ^ sw7)*8)];
      #pragma unroll
      for (int n = 0; n < 4; ++n)
        bfr[n] = *(const short8*)&Bs[cur][(wc*64 + n*16 + l15)*64 + ((slot ^ sw7)*8)];
      #pragma unroll
      for (int m = 0; m < 4; ++m)
        #pragma unroll
        for (int n = 0; n < 4; ++n)
          acc[m][n] = __builtin_amdgcn_mfma_f32_16x16x32_bf16(af[m], bfr[n], acc[m][n], 0, 0, 0);
    }
    __builtin_amdgcn_s_setprio(0);
    if (kt + 1 < nks){
      __builtin_amdgcn_s_barrier();
      __builtin_amdgcn_sched_barrier(0);
    }
  }
  #undef STAGE256

  // vectorized epilogue: per-wave 16x68 f32 scratch (16 waves x 4416 B = 70 KB of dead 128 KB LDS)
  __syncthreads();
  float* sw = ((float*)&As[0][0]) + wave*1104;
  int rbase = m0 + wr*64;
  int c0w = n0 + wc*64;
  #pragma unroll
  for (int m = 0; m < 4; ++m){
    #pragma unroll
    for (int n = 0; n < 4; ++n)
      #pragma unroll
      for (int j = 0; j < 4; ++j)
        sw[(l4*4 + j)*68 + n*16 + l15] = acc[m][n][j];
    #pragma unroll
    for (int jj = 0; jj < 4; ++jj){
      int rl = jj*4 + l4;
      f32x4a v = *(const f32x4a*)&sw[rl*68 + l15*4];
      int row = rbase + m*16 + rl;
      int col = c0w + l15*4;
      if (col + 3 < N){
        *(f32x4a*)&C[(size_t)row*N + col] = v;
      } else {
        #pragma unroll
        for (int c = 0; c < 4; ++c) if (col + c < N) C[(size_t)row*N + col + c] = v[c];
      }
    }
  }
}

// ---------------- fused: sum split-K parts (+bias) (+gate) (+bf16 resid) + layernorm -> bf16 ----------------
__global__ __launch_bounds__(256) void ln_kernel(const float* __restrict__ parts, int np,
                                                 const float* __restrict__ bias,
                                                 const bf16* __restrict__ residb,
                                                 const float* __restrict__ pg, const float* __restrict__ gb,
                                                 const float* __restrict__ g, const float* __restrict__ bta,
                                                 bf16* __restrict__ outb){
  const size_t PS = (size_t)BB*SS*E;   // partial stride
  int row = blockIdx.x;
  int b = row >> 10;
  int tid = threadIdx.x;
  __shared__ float sred[4];
  float y[3];
  float lsum = 0.f;
  #pragma unroll
  for (int i = 0; i < 3; ++i){
    int e = tid + i*256;
    float v = bias ? bias[e] : 0.f;
    for (int p = 0; p < np; ++p) v += parts[(size_t)p*PS + (size_t)row*E + e];
    if (pg){
      float ga = pg[(size_t)(b*4+0)*E + e] + pg[(size_t)(b*4+1)*E + e]
               + pg[(size_t)(b*4+2)*E + e] + pg[(size_t)(b*4+3)*E + e] + gb[e];
      v *= 1.0f / (1.0f + __expf(-ga));
    }
    if (residb) v += b2f(residb[(size_t)row*E + e]);
    y[i] = v; lsum += v;
  }
  for (int off = 32; off > 0; off >>= 1) lsum += __shfl_down(lsum, off, 64);
  int wid = tid >> 6, lane = tid & 63;
  if (lane == 0) sred[wid] = lsum;
  __syncthreads();
  float mean = (sred[0]+sred[1]+sred[2]+sred[3]) * (1.0f/E);
  __syncthreads();
  float lvar = 0.f;
  #pragma unroll
  for (int i = 0; i < 3; ++i){ float d = y[i]-mean; lvar += d*d; }
  for (int off = 32; off > 0; off >>= 1) lvar += __shfl_down(lvar, off, 64);
  if (lane == 0) sred[wid] = lvar;
  __syncthreads();
  float rstd = rsqrtf((sred[0]+sred[1]+sred[2]+sred[3]) * (1.0f/E) + EPSL);
  __syncthreads();
  #pragma unroll
  for (int i = 0; i < 3; ++i){
    int e = tid + i*256;
    outb[(size_t)row*E + e] = __float2bfloat16((y[i]-mean)*rstd*g[e] + bta[e]);
  }
}

extern "C" void kernel_launch(void* const* d_in, const int* in_sizes, int n_in,
                              void* d_out, int out_size, void* d_ws, size_t ws_size,
                              hipStream_t stream) {
  const int*   x      = (const int*)  d_in[0];
  const float* embedW = (const float*)d_in[2];
  const float* pos    = (const float*)d_in[3];
  const float* fcW    = (const float*)d_in[4];
  const float* fcB    = (const float*)d_in[5];
  const float* gW     = (const float*)d_in[6];
  const float* gB     = (const float*)d_in[7];
  const float* ln1g   = (const float*)d_in[8];
  const float* ln1b   = (const float*)d_in[9];
  const float* ln2g   = (const float*)d_in[10];
  const float* ln2b   = (const float*)d_in[11];
  const float* f1W    = (const float*)d_in[12];
  const float* f1B    = (const float*)d_in[13];
  const float* f2W    = (const float*)d_in[14];
  const float* f2B    = (const float*)d_in[15];
  const float* lnfg   = (const float*)d_in[16];
  const float* lnfb   = (const float*)d_in[17];
  const float* headW  = (const float*)d_in[18];
  float* out = (float*)d_out;

  const size_t BSE = (size_t)BB*SS*E;
  float* o    = (float*)d_ws;              // hb + vT (bf16) live here
  float* tmp  = o   + BSE;                 // 2*BSE: split-K partials
  float* ph   = tmp + 2*BSE;               // [BB*16][E]
  float* pg   = ph  + (size_t)BB*16*E;     // [BB*4][E]
  bf16* abA   = (bf16*)(pg + (size_t)BB*4*E);   // [2048][768]
  bf16* abF   = abA + BSE;                      // [2048][3072]
  bf16* WfcT  = abF + BSE*FEE;                  // [NL][768][768]
  bf16* Wf1T  = WfcT + (size_t)NL*E*E;          // [NL][3072][768]
  bf16* Wf2T  = Wf1T + (size_t)NL*FEE*E*E;      // [NL][768][3072]
  bf16* WheadT= Wf2T + (size_t)NL*FEE*E*E;      // [NPADH][768]
  bf16* hb    = (bf16*)o;
  bf16* vT    = hb + BSE;

  const int rows = BB*SS;   // 2048

  embed_kernel<<<(int)((BSE + 255)/256), 256, 0, stream>>>(x, embedW, pos, hb);

  { dim3 g(E/32, E/32, NL);        wcvt_kernel<<<g, 256, 0, stream>>>(fcW, WfcT, E, E, E); }
  { dim3 g((FEE*E)/32, E/32, NL);  wcvt_kernel<<<g, 256, 0, stream>>>(f1W, Wf1T, E, FEE*E, FEE*E); }
  { dim3 g(E/32, (FEE*E)/32, NL);  wcvt_kernel<<<g, 256, 0, stream>>>(f2W, Wf2T, FEE*E, E, E); }
  { dim3 g(NPADH/32, E/32, 1);     wcvt_kernel<<<g, 256, 0, stream>>>(headW, WheadT, E, V, NPADH); }

  for (int l = 0; l < NL; ++l){
    size_t oEE = (size_t)l*E*E, oE = (size_t)l*E, oFb = (size_t)l*FEE*E;

    prep_attn<<<BB*NH*16 + BB*16*3, 256, 0, stream>>>(hb, vT, ph);
    gate1_kernel<<<BB*4*3, 256, 0, stream>>>(ph, gW + oEE, pg);
    attn_mfma<<<BB*NH*16, 256, 0, stream>>>(hb, vT, abA);

    // fc_out: (2048x768) @ (768x768), split-K2 -> tmp partials
    { dim3 g(E/128, rows/128, 2);
      mfma_gemm<0><<<g, 256, 0, stream>>>(abA, WfcT + oEE, nullptr, tmp, rows, E, E/2, E); }

    // ln1: sum 2 parts + fcB, gate from pg/gB, + resid hb -> abA (bf16, ff1 input + ln2 resid)
    ln_kernel<<<rows, 256, 0, stream>>>(tmp, 2, fcB + oE, hb, pg, gB + oE,
                                        ln1g + oE, ln1b + oE, abA);

    // ff1: (2048x768) @ (768x3072) + gelu -> abF bf16
    { dim3 g((FEE*E)/128, rows/128, 1);
      mfma_gemm<3><<<g, 256, 0, stream>>>(abA, Wf1T + (size_t)l*FEE*E*E, f1B + oFb, abF, rows, FEE*E, E, E); }

    // ff2: (2048x3072) @ (3072x768), split-K2 -> tmp partials
    { dim3 g(E/128, rows/128, 2);
      mfma_gemm<0><<<g, 256, 0, stream>>>(abF, Wf2T + (size_t)l*FEE*E*E, nullptr, tmp, rows, E, FEE*E/2, FEE*E); }

    // ln2: sum 2 parts + f2B, + resid abA -> hb (bf16, next layer's hidden state)
    ln_kernel<<<rows, 256, 0, stream>>>(tmp, 2, f2B + oE, abA, nullptr, nullptr,
                                        ln2g + oE, ln2b + oE, hb);
  }

  // final LN: input = hb alone -> abA (head input)
  ln_kernel<<<rows, 256, 0, stream>>>(nullptr, 0, nullptr, hb, nullptr, nullptr,
                                      lnfg, lnfb, abA);
  {
    gemm256<<<(rows/256)*(NPADH/256), 1024, 0, stream>>>(abA, WheadT, out, rows, V, E, rows/256);
  }
}